// Round 1
// baseline (603.887 us; speedup 1.0000x reference)
//
#include <hip/hip_runtime.h>
#include <math.h>

// Problem dims (fixed by the reference)
#define S_DIM 4096
#define H_DIM 4096
#define HC_N 4
#define HD_DIM 16384   // HC_N * H_DIM
#define MIXN 24        // (2+HC)*HC
#define SINK_IT 20

typedef float f32x4 __attribute__((ext_vector_type(4)));
typedef __bf16 bf16x8 __attribute__((ext_vector_type(8)));
typedef unsigned short u16x8 __attribute__((ext_vector_type(8)));
typedef unsigned short u16x4 __attribute__((ext_vector_type(4)));

__device__ __forceinline__ unsigned short f2bf(float f) {
  unsigned u = __builtin_bit_cast(unsigned, f);
  u += 0x7FFFu + ((u >> 16) & 1u);   // round-to-nearest-even
  return (unsigned short)(u >> 16);
}
__device__ __forceinline__ float bf2f(unsigned short h) {
  return __builtin_bit_cast(float, (unsigned)h << 16);
}

// ---------------------------------------------------------------------------
// K0: w_inner fp32 -> bf16
__global__ __launch_bounds__(256) void k_w2bf(const float* __restrict__ w,
                                              unsigned short* __restrict__ wb) {
  const size_t i = (size_t)(blockIdx.x * 256 + threadIdx.x) * 8;
  f32x4 a = *(const f32x4*)(w + i);
  f32x4 b = *(const f32x4*)(w + i + 4);
  u16x8 o;
  o[0] = f2bf(a.x); o[1] = f2bf(a.y); o[2] = f2bf(a.z); o[3] = f2bf(a.w);
  o[4] = f2bf(b.x); o[5] = f2bf(b.y); o[6] = f2bf(b.z); o[7] = f2bf(b.w);
  *(u16x8*)(wb + i) = o;
}

// ---------------------------------------------------------------------------
// K1: per-row mixes_raw[s][24] = flat[s,:] . hc_fn[m,:]  and sumsq[s]
// 4 rows per block (amortizes hc_fn L2 reads), 256 threads.
__global__ __launch_bounds__(256) void k_mixes(const float* __restrict__ hs,
                                               const float* __restrict__ fn,
                                               float* __restrict__ mixraw,
                                               float* __restrict__ sumsq) {
  const int tid = threadIdx.x;
  const int b = blockIdx.x;          // rows 4b..4b+3
  const int lane = tid & 63, wave = tid >> 6;

  float acc[HC_N][MIXN];
  float ss[HC_N];
#pragma unroll
  for (int r = 0; r < HC_N; r++) {
    ss[r] = 0.f;
#pragma unroll
    for (int m = 0; m < MIXN; m++) acc[r][m] = 0.f;
  }

  const size_t rowbase = (size_t)b * HC_N * HD_DIM;
  for (int it = 0; it < 16; ++it) {
    const int d4 = it * 256 + tid;    // float4 index within 16384-long row
    f32x4 h4[HC_N];
#pragma unroll
    for (int r = 0; r < HC_N; r++) {
      h4[r] = *(const f32x4*)(hs + rowbase + (size_t)r * HD_DIM + (size_t)d4 * 4);
      ss[r] += h4[r].x * h4[r].x + h4[r].y * h4[r].y + h4[r].z * h4[r].z + h4[r].w * h4[r].w;
    }
#pragma unroll
    for (int m = 0; m < MIXN; m++) {
      f32x4 fv = *(const f32x4*)(fn + (size_t)m * HD_DIM + (size_t)d4 * 4);
#pragma unroll
      for (int r = 0; r < HC_N; r++)
        acc[r][m] += h4[r].x * fv.x + h4[r].y * fv.y + h4[r].z * fv.z + h4[r].w * fv.w;
    }
  }

  __shared__ float red[4][100];
#pragma unroll
  for (int r = 0; r < HC_N; r++) {
#pragma unroll
    for (int m = 0; m < MIXN; m++) {
      float v = acc[r][m];
#pragma unroll
      for (int off = 32; off >= 1; off >>= 1) v += __shfl_xor(v, off, 64);
      if (lane == 0) red[wave][r * MIXN + m] = v;
    }
    float v = ss[r];
#pragma unroll
    for (int off = 32; off >= 1; off >>= 1) v += __shfl_xor(v, off, 64);
    if (lane == 0) red[wave][96 + r] = v;
  }
  __syncthreads();
  if (tid < 100) {
    float t = red[0][tid] + red[1][tid] + red[2][tid] + red[3][tid];
    if (tid < 96)
      mixraw[(size_t)(b * 4 + tid / 24) * MIXN + (tid % 24)] = t;
    else
      sumsq[b * 4 + (tid - 96)] = t;
  }
}

// ---------------------------------------------------------------------------
// K2: gates = {pre[4], post[4], sinkhorn(comb)[16]} per row
__global__ __launch_bounds__(256) void k_gates(const float* __restrict__ mixraw,
                                               const float* __restrict__ sumsq,
                                               const float* __restrict__ hbase,
                                               const float* __restrict__ hscale,
                                               float* __restrict__ gates) {
  const int row = blockIdx.x * 256 + threadIdx.x;
  const float rs = rsqrtf(sumsq[row] * (1.0f / HD_DIM) + 1e-6f);
  const float ps = hscale[0], qs = hscale[1], cs = hscale[2];
  const float* mr = mixraw + (size_t)row * MIXN;
  float g[MIXN];
#pragma unroll
  for (int m = 0; m < MIXN; m++) {
    const float sc = (m < 4) ? ps : ((m < 8) ? qs : cs);
    const float x = mr[m] * rs * sc + hbase[m];
    g[m] = 1.0f / (1.0f + expf(-x)) + 1e-6f;
  }
  // 20-iter Sinkhorn on g[8..23] viewed as c[i][j] = g[8+i*4+j]
  for (int t = 0; t < SINK_IT; t++) {
#pragma unroll
    for (int i = 0; i < 4; i++) {
      const float s = g[8 + i * 4 + 0] + g[8 + i * 4 + 1] + g[8 + i * 4 + 2] + g[8 + i * 4 + 3] + 1e-6f;
#pragma unroll
      for (int j = 0; j < 4; j++) g[8 + i * 4 + j] /= s;
    }
#pragma unroll
    for (int j = 0; j < 4; j++) {
      const float s = g[8 + 0 + j] + g[8 + 4 + j] + g[8 + 8 + j] + g[8 + 12 + j] + 1e-6f;
#pragma unroll
      for (int i = 0; i < 4; i++) g[8 + i * 4 + j] /= s;
    }
  }
  float* go = gates + (size_t)row * MIXN;
#pragma unroll
  for (int m = 0; m < MIXN; m++) go[m] = g[m];
}

// ---------------------------------------------------------------------------
// K3: reduced = pre . hs  -> RMSNorm -> normed (bf16).  One block per row s.
__global__ __launch_bounds__(256) void k_reduce_norm(const float* __restrict__ hs,
                                                     const float* __restrict__ gates,
                                                     const float* __restrict__ nw,
                                                     unsigned short* __restrict__ normed) {
  const int s = blockIdx.x, tid = threadIdx.x;
  const int lane = tid & 63, wave = tid >> 6;
  const float* g = gates + (size_t)s * MIXN;
  const float p0 = g[0], p1 = g[1], p2 = g[2], p3 = g[3];
  const size_t base = (size_t)s * HC_N * H_DIM;

  f32x4 red[4];
  float ssq = 0.f;
#pragma unroll
  for (int it = 0; it < 4; ++it) {
    const int d4 = it * 256 + tid;
    f32x4 a = *(const f32x4*)(hs + base + (size_t)0 * H_DIM + (size_t)d4 * 4);
    f32x4 b = *(const f32x4*)(hs + base + (size_t)1 * H_DIM + (size_t)d4 * 4);
    f32x4 c = *(const f32x4*)(hs + base + (size_t)2 * H_DIM + (size_t)d4 * 4);
    f32x4 d = *(const f32x4*)(hs + base + (size_t)3 * H_DIM + (size_t)d4 * 4);
    f32x4 v = p0 * a + p1 * b + p2 * c + p3 * d;
    red[it] = v;
    ssq += v.x * v.x + v.y * v.y + v.z * v.z + v.w * v.w;
  }
#pragma unroll
  for (int off = 32; off >= 1; off >>= 1) ssq += __shfl_xor(ssq, off, 64);
  __shared__ float ls[4];
  if (lane == 0) ls[wave] = ssq;
  __syncthreads();
  const float tot = ls[0] + ls[1] + ls[2] + ls[3];
  const float nr = rsqrtf(tot * (1.0f / H_DIM) + 1e-6f);
#pragma unroll
  for (int it = 0; it < 4; ++it) {
    const int d4 = it * 256 + tid;
    f32x4 w = *(const f32x4*)(nw + (size_t)d4 * 4);
    f32x4 v = red[it] * nr;
    v = v * w;
    u16x4 o;
    o[0] = f2bf(v.x); o[1] = f2bf(v.y); o[2] = f2bf(v.z); o[3] = f2bf(v.w);
    *(u16x4*)(normed + (size_t)s * H_DIM + (size_t)d4 * 4) = o;
  }
}

// ---------------------------------------------------------------------------
// K4: bf16 GEMM  C[s][e] = sum_d A[s][d] * B[e][d]   (m97-style 128x128 tile)
__device__ __forceinline__ void gload_lds16(const unsigned short* g, unsigned short* l) {
  __builtin_amdgcn_global_load_lds(
      (const __attribute__((address_space(1))) unsigned int*)(const void*)g,
      (__attribute__((address_space(3))) unsigned int*)(void*)l, 16, 0, 0);
}

__global__ __launch_bounds__(256) void k_gemm(const unsigned short* __restrict__ A,
                                              const unsigned short* __restrict__ B,
                                              unsigned short* __restrict__ C) {
  __shared__ __align__(16) unsigned short sA[128 * 32];
  __shared__ __align__(16) unsigned short sB[128 * 32];
  const int tid = threadIdx.x;
  const int lane = tid & 63, wave = tid >> 6;
  const int bm = blockIdx.y, bn = blockIdx.x;
  const int wm = wave >> 1, wn = wave & 1;

  f32x4 zero = {0.f, 0.f, 0.f, 0.f};
  f32x4 acc[4][4];
#pragma unroll
  for (int mi = 0; mi < 4; mi++)
#pragma unroll
    for (int ni = 0; ni < 4; ni++) acc[mi][ni] = zero;

  const int strow = lane >> 2;          // 0..15
  const int stk = (lane & 3) * 8;       // 0,8,16,24
  const unsigned short* ga = A + (size_t)(bm * 128) * 4096;
  const unsigned short* gb = B + (size_t)(bn * 128) * 4096;
  const int c0 = wave * 2, c1 = wave * 2 + 1;

  for (int kk = 0; kk < 4096; kk += 32) {
    // stage A/B tiles: 8 x (64 lanes x 16B) chunks each
    gload_lds16(ga + (size_t)(c0 * 16 + strow) * 4096 + kk + stk, sA + c0 * 512);
    gload_lds16(ga + (size_t)(c1 * 16 + strow) * 4096 + kk + stk, sA + c1 * 512);
    gload_lds16(gb + (size_t)(c0 * 16 + strow) * 4096 + kk + stk, sB + c0 * 512);
    gload_lds16(gb + (size_t)(c1 * 16 + strow) * 4096 + kk + stk, sB + c1 * 512);
    __syncthreads();

    const int rb = lane & 15, kq = (lane >> 4) * 8;
    bf16x8 af[4], bfr[4];
#pragma unroll
    for (int mi = 0; mi < 4; mi++)
      af[mi] = *(const bf16x8*)(sA + (wm * 64 + mi * 16 + rb) * 32 + kq);
#pragma unroll
    for (int ni = 0; ni < 4; ni++)
      bfr[ni] = *(const bf16x8*)(sB + (wn * 64 + ni * 16 + rb) * 32 + kq);
#pragma unroll
    for (int mi = 0; mi < 4; mi++)
#pragma unroll
      for (int ni = 0; ni < 4; ni++)
        acc[mi][ni] = __builtin_amdgcn_mfma_f32_16x16x32_bf16(af[mi], bfr[ni], acc[mi][ni], 0, 0, 0);
    __syncthreads();
  }

  const int cr = (lane >> 4) * 4, cc = lane & 15;
#pragma unroll
  for (int mi = 0; mi < 4; mi++)
#pragma unroll
    for (int ni = 0; ni < 4; ni++)
#pragma unroll
      for (int j = 0; j < 4; j++) {
        const int row = bm * 128 + wm * 64 + mi * 16 + cr + j;
        const int col = bn * 128 + wn * 64 + ni * 16 + cc;
        C[(size_t)row * 4096 + col] = f2bf(acc[mi][ni][j]);
      }
}

// ---------------------------------------------------------------------------
// K5: expanded[s][h][d] = post[h]*out[s][d] + sum_k comb[h][k]*hs[s][k][d]
__global__ __launch_bounds__(256) void k_expand(const float* __restrict__ hs,
                                                const unsigned short* __restrict__ outb,
                                                const float* __restrict__ gates,
                                                float* __restrict__ y) {
  const int s = blockIdx.x, tid = threadIdx.x;
  const float* g = gates + (size_t)s * MIXN;
  float post[4], cb[4][4];
#pragma unroll
  for (int h = 0; h < 4; h++) post[h] = g[4 + h];
#pragma unroll
  for (int h = 0; h < 4; h++)
#pragma unroll
    for (int k = 0; k < 4; k++) cb[h][k] = g[8 + h * 4 + k];

  const size_t base = (size_t)s * HC_N * H_DIM;
#pragma unroll
  for (int it = 0; it < 4; ++it) {
    const int d4 = it * 256 + tid;
    f32x4 hv[4];
#pragma unroll
    for (int k = 0; k < 4; k++)
      hv[k] = *(const f32x4*)(hs + base + (size_t)k * H_DIM + (size_t)d4 * 4);
    u16x4 ob = *(const u16x4*)(outb + (size_t)s * H_DIM + (size_t)d4 * 4);
    f32x4 o = {bf2f(ob[0]), bf2f(ob[1]), bf2f(ob[2]), bf2f(ob[3])};
#pragma unroll
    for (int h = 0; h < 4; h++) {
      f32x4 e = post[h] * o + cb[h][0] * hv[0] + cb[h][1] * hv[1] + cb[h][2] * hv[2] + cb[h][3] * hv[3];
      *(f32x4*)(y + base + (size_t)h * H_DIM + (size_t)d4 * 4) = e;
    }
  }
}

// ---------------------------------------------------------------------------
extern "C" void kernel_launch(void* const* d_in, const int* in_sizes, int n_in,
                              void* d_out, int out_size, void* d_ws, size_t ws_size,
                              hipStream_t stream) {
  const float* hs = (const float*)d_in[0];      // [1,4096,4,4096]
  const float* fn = (const float*)d_in[1];      // [24,16384]
  const float* hbase = (const float*)d_in[2];   // [24]
  const float* hscale = (const float*)d_in[3];  // [3]
  const float* nw = (const float*)d_in[4];      // [4096]
  const float* wi = (const float*)d_in[5];      // [4096,4096]
  float* y = (float*)d_out;                     // [1,4096,4,4096] fp32

  char* ws = (char*)d_ws;
  float* mixraw = (float*)(ws);                            // 4096*24*4   = 393216
  float* sumsq = (float*)(ws + 393216);                    // 4096*4      = 16384
  float* gates = (float*)(ws + 409600);                    // 4096*24*4   = 393216
  unsigned short* normed = (unsigned short*)(ws + 1048576);            // 32MB bf16
  unsigned short* wb = (unsigned short*)(ws + 1048576 + 33554432);     // 32MB bf16
  unsigned short* outb = (unsigned short*)(ws + 1048576 + 2 * 33554432); // 32MB bf16
  // total ws use: ~97MB

  k_w2bf<<<8192, 256, 0, stream>>>(wi, wb);
  k_mixes<<<1024, 256, 0, stream>>>(hs, fn, mixraw, sumsq);
  k_gates<<<16, 256, 0, stream>>>(mixraw, sumsq, hbase, hscale, gates);
  k_reduce_norm<<<4096, 256, 0, stream>>>(hs, gates, nw, normed);
  k_gemm<<<dim3(32, 32), 256, 0, stream>>>(normed, wb, outb);
  k_expand<<<4096, 256, 0, stream>>>(hs, outb, gates, y);
}

// Round 2
// 490.105 us; speedup vs baseline: 1.2322x; 1.2322x over previous
//
#include <hip/hip_runtime.h>
#include <math.h>

// Problem dims (fixed by the reference)
#define S_DIM 4096
#define H_DIM 4096
#define HC_N 4
#define HD_DIM 16384   // HC_N * H_DIM
#define MIXN 24        // (2+HC)*HC
#define SINK_IT 20

typedef float f32x4 __attribute__((ext_vector_type(4)));
typedef __bf16 bf16x8 __attribute__((ext_vector_type(8)));
typedef unsigned short u16x8 __attribute__((ext_vector_type(8)));
typedef unsigned short u16x4 __attribute__((ext_vector_type(4)));

__device__ __forceinline__ unsigned short f2bf(float f) {
  unsigned u = __builtin_bit_cast(unsigned, f);
  u += 0x7FFFu + ((u >> 16) & 1u);   // round-to-nearest-even
  return (unsigned short)(u >> 16);
}
__device__ __forceinline__ float bf2f(unsigned short h) {
  return __builtin_bit_cast(float, (unsigned)h << 16);
}

// ---------------------------------------------------------------------------
// K0: w_inner fp32 -> bf16
__global__ __launch_bounds__(256) void k_w2bf(const float* __restrict__ w,
                                              unsigned short* __restrict__ wb) {
  const size_t i = (size_t)(blockIdx.x * 256 + threadIdx.x) * 8;
  f32x4 a = *(const f32x4*)(w + i);
  f32x4 b = *(const f32x4*)(w + i + 4);
  u16x8 o;
  o[0] = f2bf(a.x); o[1] = f2bf(a.y); o[2] = f2bf(a.z); o[3] = f2bf(a.w);
  o[4] = f2bf(b.x); o[5] = f2bf(b.y); o[6] = f2bf(b.z); o[7] = f2bf(b.w);
  *(u16x8*)(wb + i) = o;
}

// ---------------------------------------------------------------------------
// K1: per-row mixes_raw[s][24] = flat[s,:] . hc_fn[m,:]  and sumsq[s]
// 4 rows per block. m-split across waves (wave w owns m in [6w,6w+6)) so the
// accumulator is acc[4][6]=24 VGPRs (v1 had acc[4][24]=96 -> scratch spill).
// hs chunks staged through LDS once per block; all 4 waves re-read from LDS.
__global__ __launch_bounds__(256) void k_mixes(const float* __restrict__ hs,
                                               const float* __restrict__ fn,
                                               float* __restrict__ mixraw,
                                               float* __restrict__ sumsq) {
  __shared__ __align__(16) float lds[HC_N][1024];
  const int tid = threadIdx.x;
  const int b = blockIdx.x;          // rows 4b..4b+3
  const int lane = tid & 63, wave = tid >> 6;
  const int mbase = wave * 6;

  float acc[HC_N][6];
  float ss[HC_N];
#pragma unroll
  for (int r = 0; r < HC_N; r++) {
    ss[r] = 0.f;
#pragma unroll
    for (int j = 0; j < 6; j++) acc[r][j] = 0.f;
  }

  const size_t rowbase = (size_t)b * HC_N * HD_DIM;
  for (int it = 0; it < 16; ++it) {
    __syncthreads();   // previous compute done before overwriting LDS
#pragma unroll
    for (int r = 0; r < HC_N; r++) {
      f32x4 v = *(const f32x4*)(hs + rowbase + (size_t)r * HD_DIM + it * 1024 + tid * 4);
      *(f32x4*)(&lds[r][tid * 4]) = v;
    }
    __syncthreads();
#pragma unroll
    for (int ii = 0; ii < 4; ii++) {
      const int c4 = ii * 64 + lane;   // f32x4 index within the 1024-float chunk
      f32x4 h4[HC_N];
#pragma unroll
      for (int r = 0; r < HC_N; r++) h4[r] = *(const f32x4*)(&lds[r][c4 * 4]);
      if (wave == 0) {
#pragma unroll
        for (int r = 0; r < HC_N; r++)
          ss[r] += h4[r].x * h4[r].x + h4[r].y * h4[r].y + h4[r].z * h4[r].z + h4[r].w * h4[r].w;
      }
#pragma unroll
      for (int j = 0; j < 6; j++) {
        f32x4 fv = *(const f32x4*)(fn + (size_t)(mbase + j) * HD_DIM + it * 1024 + c4 * 4);
#pragma unroll
        for (int r = 0; r < HC_N; r++)
          acc[r][j] += h4[r].x * fv.x + h4[r].y * fv.y + h4[r].z * fv.z + h4[r].w * fv.w;
      }
    }
  }

  // per-wave shuffle reduction; each wave owns its 6 m values outright
#pragma unroll
  for (int r = 0; r < HC_N; r++) {
#pragma unroll
    for (int j = 0; j < 6; j++) {
      float v = acc[r][j];
#pragma unroll
      for (int off = 32; off >= 1; off >>= 1) v += __shfl_xor(v, off, 64);
      if (lane == 0) mixraw[(size_t)(b * 4 + r) * MIXN + mbase + j] = v;
    }
  }
  if (wave == 0) {
#pragma unroll
    for (int r = 0; r < HC_N; r++) {
      float v = ss[r];
#pragma unroll
      for (int off = 32; off >= 1; off >>= 1) v += __shfl_xor(v, off, 64);
      if (lane == 0) sumsq[b * 4 + r] = v;
    }
  }
}

// ---------------------------------------------------------------------------
// K2: gates = {pre[4], post[4], sinkhorn(comb)[16]} per row
__global__ __launch_bounds__(256) void k_gates(const float* __restrict__ mixraw,
                                               const float* __restrict__ sumsq,
                                               const float* __restrict__ hbase,
                                               const float* __restrict__ hscale,
                                               float* __restrict__ gates) {
  const int row = blockIdx.x * 256 + threadIdx.x;
  const float rs = rsqrtf(sumsq[row] * (1.0f / HD_DIM) + 1e-6f);
  const float ps = hscale[0], qs = hscale[1], cs = hscale[2];
  const float* mr = mixraw + (size_t)row * MIXN;
  float g[MIXN];
#pragma unroll
  for (int m = 0; m < MIXN; m++) {
    const float sc = (m < 4) ? ps : ((m < 8) ? qs : cs);
    const float x = mr[m] * rs * sc + hbase[m];
    g[m] = 1.0f / (1.0f + expf(-x)) + 1e-6f;
  }
  // 20-iter Sinkhorn on g[8..23] viewed as c[i][j] = g[8+i*4+j]
  for (int t = 0; t < SINK_IT; t++) {
#pragma unroll
    for (int i = 0; i < 4; i++) {
      const float s = g[8 + i * 4 + 0] + g[8 + i * 4 + 1] + g[8 + i * 4 + 2] + g[8 + i * 4 + 3] + 1e-6f;
#pragma unroll
      for (int j = 0; j < 4; j++) g[8 + i * 4 + j] /= s;
    }
#pragma unroll
    for (int j = 0; j < 4; j++) {
      const float s = g[8 + 0 + j] + g[8 + 4 + j] + g[8 + 8 + j] + g[8 + 12 + j] + 1e-6f;
#pragma unroll
      for (int i = 0; i < 4; i++) g[8 + i * 4 + j] /= s;
    }
  }
  float* go = gates + (size_t)row * MIXN;
#pragma unroll
  for (int m = 0; m < MIXN; m++) go[m] = g[m];
}

// ---------------------------------------------------------------------------
// K3: reduced = pre . hs  -> RMSNorm -> normed (bf16).  One block per row s.
__global__ __launch_bounds__(256) void k_reduce_norm(const float* __restrict__ hs,
                                                     const float* __restrict__ gates,
                                                     const float* __restrict__ nw,
                                                     unsigned short* __restrict__ normed) {
  const int s = blockIdx.x, tid = threadIdx.x;
  const int lane = tid & 63, wave = tid >> 6;
  const float* g = gates + (size_t)s * MIXN;
  const float p0 = g[0], p1 = g[1], p2 = g[2], p3 = g[3];
  const size_t base = (size_t)s * HC_N * H_DIM;

  f32x4 red[4];
  float ssq = 0.f;
#pragma unroll
  for (int it = 0; it < 4; ++it) {
    const int d4 = it * 256 + tid;
    f32x4 a = *(const f32x4*)(hs + base + (size_t)0 * H_DIM + (size_t)d4 * 4);
    f32x4 b = *(const f32x4*)(hs + base + (size_t)1 * H_DIM + (size_t)d4 * 4);
    f32x4 c = *(const f32x4*)(hs + base + (size_t)2 * H_DIM + (size_t)d4 * 4);
    f32x4 d = *(const f32x4*)(hs + base + (size_t)3 * H_DIM + (size_t)d4 * 4);
    f32x4 v = p0 * a + p1 * b + p2 * c + p3 * d;
    red[it] = v;
    ssq += v.x * v.x + v.y * v.y + v.z * v.z + v.w * v.w;
  }
#pragma unroll
  for (int off = 32; off >= 1; off >>= 1) ssq += __shfl_xor(ssq, off, 64);
  __shared__ float ls[4];
  if (lane == 0) ls[wave] = ssq;
  __syncthreads();
  const float tot = ls[0] + ls[1] + ls[2] + ls[3];
  const float nr = rsqrtf(tot * (1.0f / H_DIM) + 1e-6f);
#pragma unroll
  for (int it = 0; it < 4; ++it) {
    const int d4 = it * 256 + tid;
    f32x4 w = *(const f32x4*)(nw + (size_t)d4 * 4);
    f32x4 v = red[it] * nr;
    v = v * w;
    u16x4 o;
    o[0] = f2bf(v.x); o[1] = f2bf(v.y); o[2] = f2bf(v.z); o[3] = f2bf(v.w);
    *(u16x4*)(normed + (size_t)s * H_DIM + (size_t)d4 * 4) = o;
  }
}

// ---------------------------------------------------------------------------
// K4: bf16 GEMM  C[s][e] = sum_d A[s][d] * B[e][d]   (m97-style 128x128 tile)
__device__ __forceinline__ void gload_lds16(const unsigned short* g, unsigned short* l) {
  __builtin_amdgcn_global_load_lds(
      (const __attribute__((address_space(1))) unsigned int*)(const void*)g,
      (__attribute__((address_space(3))) unsigned int*)(void*)l, 16, 0, 0);
}

__global__ __launch_bounds__(256) void k_gemm(const unsigned short* __restrict__ A,
                                              const unsigned short* __restrict__ B,
                                              unsigned short* __restrict__ C) {
  __shared__ __align__(16) unsigned short sA[128 * 32];
  __shared__ __align__(16) unsigned short sB[128 * 32];
  const int tid = threadIdx.x;
  const int lane = tid & 63, wave = tid >> 6;
  const int bm = blockIdx.y, bn = blockIdx.x;
  const int wm = wave >> 1, wn = wave & 1;

  f32x4 zero = {0.f, 0.f, 0.f, 0.f};
  f32x4 acc[4][4];
#pragma unroll
  for (int mi = 0; mi < 4; mi++)
#pragma unroll
    for (int ni = 0; ni < 4; ni++) acc[mi][ni] = zero;

  const int strow = lane >> 2;          // 0..15
  const int stk = (lane & 3) * 8;       // 0,8,16,24
  const unsigned short* ga = A + (size_t)(bm * 128) * 4096;
  const unsigned short* gb = B + (size_t)(bn * 128) * 4096;
  const int c0 = wave * 2, c1 = wave * 2 + 1;

  for (int kk = 0; kk < 4096; kk += 32) {
    // stage A/B tiles: 8 x (64 lanes x 16B) chunks each
    gload_lds16(ga + (size_t)(c0 * 16 + strow) * 4096 + kk + stk, sA + c0 * 512);
    gload_lds16(ga + (size_t)(c1 * 16 + strow) * 4096 + kk + stk, sA + c1 * 512);
    gload_lds16(gb + (size_t)(c0 * 16 + strow) * 4096 + kk + stk, sB + c0 * 512);
    gload_lds16(gb + (size_t)(c1 * 16 + strow) * 4096 + kk + stk, sB + c1 * 512);
    __syncthreads();

    const int rb = lane & 15, kq = (lane >> 4) * 8;
    bf16x8 af[4], bfr[4];
#pragma unroll
    for (int mi = 0; mi < 4; mi++)
      af[mi] = *(const bf16x8*)(sA + (wm * 64 + mi * 16 + rb) * 32 + kq);
#pragma unroll
    for (int ni = 0; ni < 4; ni++)
      bfr[ni] = *(const bf16x8*)(sB + (wn * 64 + ni * 16 + rb) * 32 + kq);
#pragma unroll
    for (int mi = 0; mi < 4; mi++)
#pragma unroll
      for (int ni = 0; ni < 4; ni++)
        acc[mi][ni] = __builtin_amdgcn_mfma_f32_16x16x32_bf16(af[mi], bfr[ni], acc[mi][ni], 0, 0, 0);
    __syncthreads();
  }

  const int cr = (lane >> 4) * 4, cc = lane & 15;
#pragma unroll
  for (int mi = 0; mi < 4; mi++)
#pragma unroll
    for (int ni = 0; ni < 4; ni++)
#pragma unroll
      for (int j = 0; j < 4; j++) {
        const int row = bm * 128 + wm * 64 + mi * 16 + cr + j;
        const int col = bn * 128 + wn * 64 + ni * 16 + cc;
        C[(size_t)row * 4096 + col] = f2bf(acc[mi][ni][j]);
      }
}

// ---------------------------------------------------------------------------
// K5: expanded[s][h][d] = post[h]*out[s][d] + sum_k comb[h][k]*hs[s][k][d]
__global__ __launch_bounds__(256) void k_expand(const float* __restrict__ hs,
                                                const unsigned short* __restrict__ outb,
                                                const float* __restrict__ gates,
                                                float* __restrict__ y) {
  const int s = blockIdx.x, tid = threadIdx.x;
  const float* g = gates + (size_t)s * MIXN;
  float post[4], cb[4][4];
#pragma unroll
  for (int h = 0; h < 4; h++) post[h] = g[4 + h];
#pragma unroll
  for (int h = 0; h < 4; h++)
#pragma unroll
    for (int k = 0; k < 4; k++) cb[h][k] = g[8 + h * 4 + k];

  const size_t base = (size_t)s * HC_N * H_DIM;
#pragma unroll
  for (int it = 0; it < 4; ++it) {
    const int d4 = it * 256 + tid;
    f32x4 hv[4];
#pragma unroll
    for (int k = 0; k < 4; k++)
      hv[k] = *(const f32x4*)(hs + base + (size_t)k * H_DIM + (size_t)d4 * 4);
    u16x4 ob = *(const u16x4*)(outb + (size_t)s * H_DIM + (size_t)d4 * 4);
    f32x4 o = {bf2f(ob[0]), bf2f(ob[1]), bf2f(ob[2]), bf2f(ob[3])};
#pragma unroll
    for (int h = 0; h < 4; h++) {
      f32x4 e = post[h] * o + cb[h][0] * hv[0] + cb[h][1] * hv[1] + cb[h][2] * hv[2] + cb[h][3] * hv[3];
      *(f32x4*)(y + base + (size_t)h * H_DIM + (size_t)d4 * 4) = e;
    }
  }
}

// ---------------------------------------------------------------------------
extern "C" void kernel_launch(void* const* d_in, const int* in_sizes, int n_in,
                              void* d_out, int out_size, void* d_ws, size_t ws_size,
                              hipStream_t stream) {
  const float* hs = (const float*)d_in[0];      // [1,4096,4,4096]
  const float* fn = (const float*)d_in[1];      // [24,16384]
  const float* hbase = (const float*)d_in[2];   // [24]
  const float* hscale = (const float*)d_in[3];  // [3]
  const float* nw = (const float*)d_in[4];      // [4096]
  const float* wi = (const float*)d_in[5];      // [4096,4096]
  float* y = (float*)d_out;                     // [1,4096,4,4096] fp32

  char* ws = (char*)d_ws;
  float* mixraw = (float*)(ws);                            // 4096*24*4   = 393216
  float* sumsq = (float*)(ws + 393216);                    // 4096*4      = 16384
  float* gates = (float*)(ws + 409600);                    // 4096*24*4   = 393216
  unsigned short* normed = (unsigned short*)(ws + 1048576);            // 32MB bf16
  unsigned short* wb = (unsigned short*)(ws + 1048576 + 33554432);     // 32MB bf16
  unsigned short* outb = (unsigned short*)(ws + 1048576 + 2 * 33554432); // 32MB bf16
  // total ws use: ~97MB

  k_w2bf<<<8192, 256, 0, stream>>>(wi, wb);
  k_mixes<<<1024, 256, 0, stream>>>(hs, fn, mixraw, sumsq);
  k_gates<<<16, 256, 0, stream>>>(mixraw, sumsq, hbase, hscale, gates);
  k_reduce_norm<<<4096, 256, 0, stream>>>(hs, gates, nw, normed);
  k_gemm<<<dim3(32, 32), 256, 0, stream>>>(normed, wb, outb);
  k_expand<<<4096, 256, 0, stream>>>(hs, outb, gates, y);
}

// Round 3
// 487.089 us; speedup vs baseline: 1.2398x; 1.0062x over previous
//
#include <hip/hip_runtime.h>
#include <math.h>

// Problem dims (fixed by the reference)
#define S_DIM 4096
#define H_DIM 4096
#define HC_N 4
#define HD_DIM 16384   // HC_N * H_DIM
#define MIXN 24        // (2+HC)*HC
#define SINK_IT 20

typedef float f32x4 __attribute__((ext_vector_type(4)));
typedef __bf16 bf16x8 __attribute__((ext_vector_type(8)));
typedef unsigned short u16x8 __attribute__((ext_vector_type(8)));
typedef unsigned short u16x4 __attribute__((ext_vector_type(4)));

__device__ __forceinline__ unsigned short f2bf(float f) {
  unsigned u = __builtin_bit_cast(unsigned, f);
  u += 0x7FFFu + ((u >> 16) & 1u);   // round-to-nearest-even
  return (unsigned short)(u >> 16);
}
__device__ __forceinline__ float bf2f(unsigned short h) {
  return __builtin_bit_cast(float, (unsigned)h << 16);
}

// ---------------------------------------------------------------------------
// K0: w_inner fp32 -> bf16
__global__ __launch_bounds__(256) void k_w2bf(const float* __restrict__ w,
                                              unsigned short* __restrict__ wb) {
  const size_t i = (size_t)(blockIdx.x * 256 + threadIdx.x) * 8;
  f32x4 a = *(const f32x4*)(w + i);
  f32x4 b = *(const f32x4*)(w + i + 4);
  u16x8 o;
  o[0] = f2bf(a.x); o[1] = f2bf(a.y); o[2] = f2bf(a.z); o[3] = f2bf(a.w);
  o[4] = f2bf(b.x); o[5] = f2bf(b.y); o[6] = f2bf(b.z); o[7] = f2bf(b.w);
  *(u16x8*)(wb + i) = o;
}

// ---------------------------------------------------------------------------
// K1: per-row mixes_raw[s][24] = flat[s,:] . hc_fn[m,:]  and sumsq[s]
// 4 rows per block, m-split across waves (acc[4][6] stays in VGPRs).
__global__ __launch_bounds__(256) void k_mixes(const float* __restrict__ hs,
                                               const float* __restrict__ fn,
                                               float* __restrict__ mixraw,
                                               float* __restrict__ sumsq) {
  __shared__ __align__(16) float lds[HC_N][1024];
  const int tid = threadIdx.x;
  const int b = blockIdx.x;          // rows 4b..4b+3
  const int lane = tid & 63, wave = tid >> 6;
  const int mbase = wave * 6;

  float acc[HC_N][6];
  float ss[HC_N];
#pragma unroll
  for (int r = 0; r < HC_N; r++) {
    ss[r] = 0.f;
#pragma unroll
    for (int j = 0; j < 6; j++) acc[r][j] = 0.f;
  }

  const size_t rowbase = (size_t)b * HC_N * HD_DIM;
  for (int it = 0; it < 16; ++it) {
    __syncthreads();   // previous compute done before overwriting LDS
#pragma unroll
    for (int r = 0; r < HC_N; r++) {
      f32x4 v = *(const f32x4*)(hs + rowbase + (size_t)r * HD_DIM + it * 1024 + tid * 4);
      *(f32x4*)(&lds[r][tid * 4]) = v;
    }
    __syncthreads();
#pragma unroll
    for (int ii = 0; ii < 4; ii++) {
      const int c4 = ii * 64 + lane;   // f32x4 index within the 1024-float chunk
      f32x4 h4[HC_N];
#pragma unroll
      for (int r = 0; r < HC_N; r++) h4[r] = *(const f32x4*)(&lds[r][c4 * 4]);
      if (wave == 0) {
#pragma unroll
        for (int r = 0; r < HC_N; r++)
          ss[r] += h4[r].x * h4[r].x + h4[r].y * h4[r].y + h4[r].z * h4[r].z + h4[r].w * h4[r].w;
      }
#pragma unroll
      for (int j = 0; j < 6; j++) {
        f32x4 fv = *(const f32x4*)(fn + (size_t)(mbase + j) * HD_DIM + it * 1024 + c4 * 4);
#pragma unroll
        for (int r = 0; r < HC_N; r++)
          acc[r][j] += h4[r].x * fv.x + h4[r].y * fv.y + h4[r].z * fv.z + h4[r].w * fv.w;
      }
    }
  }

  // per-wave shuffle reduction; each wave owns its 6 m values outright
#pragma unroll
  for (int r = 0; r < HC_N; r++) {
#pragma unroll
    for (int j = 0; j < 6; j++) {
      float v = acc[r][j];
#pragma unroll
      for (int off = 32; off >= 1; off >>= 1) v += __shfl_xor(v, off, 64);
      if (lane == 0) mixraw[(size_t)(b * 4 + r) * MIXN + mbase + j] = v;
    }
  }
  if (wave == 0) {
#pragma unroll
    for (int r = 0; r < HC_N; r++) {
      float v = ss[r];
#pragma unroll
      for (int off = 32; off >= 1; off >>= 1) v += __shfl_xor(v, off, 64);
      if (lane == 0) sumsq[b * 4 + r] = v;
    }
  }
}

// ---------------------------------------------------------------------------
// K2: gates = {pre[4], post[4], sinkhorn(comb)[16]} per row
__global__ __launch_bounds__(256) void k_gates(const float* __restrict__ mixraw,
                                               const float* __restrict__ sumsq,
                                               const float* __restrict__ hbase,
                                               const float* __restrict__ hscale,
                                               float* __restrict__ gates) {
  const int row = blockIdx.x * 256 + threadIdx.x;
  const float rs = rsqrtf(sumsq[row] * (1.0f / HD_DIM) + 1e-6f);
  const float ps = hscale[0], qs = hscale[1], cs = hscale[2];
  const float* mr = mixraw + (size_t)row * MIXN;
  float g[MIXN];
#pragma unroll
  for (int m = 0; m < MIXN; m++) {
    const float sc = (m < 4) ? ps : ((m < 8) ? qs : cs);
    const float x = mr[m] * rs * sc + hbase[m];
    g[m] = 1.0f / (1.0f + expf(-x)) + 1e-6f;
  }
  // 20-iter Sinkhorn on g[8..23] viewed as c[i][j] = g[8+i*4+j]
  for (int t = 0; t < SINK_IT; t++) {
#pragma unroll
    for (int i = 0; i < 4; i++) {
      const float s = g[8 + i * 4 + 0] + g[8 + i * 4 + 1] + g[8 + i * 4 + 2] + g[8 + i * 4 + 3] + 1e-6f;
#pragma unroll
      for (int j = 0; j < 4; j++) g[8 + i * 4 + j] /= s;
    }
#pragma unroll
    for (int j = 0; j < 4; j++) {
      const float s = g[8 + 0 + j] + g[8 + 4 + j] + g[8 + 8 + j] + g[8 + 12 + j] + 1e-6f;
#pragma unroll
      for (int i = 0; i < 4; i++) g[8 + i * 4 + j] /= s;
    }
  }
  float* go = gates + (size_t)row * MIXN;
#pragma unroll
  for (int m = 0; m < MIXN; m++) go[m] = g[m];
}

// ---------------------------------------------------------------------------
// K3: reduced = pre . hs  -> RMSNorm -> normed (bf16).  One block per row s.
__global__ __launch_bounds__(256) void k_reduce_norm(const float* __restrict__ hs,
                                                     const float* __restrict__ gates,
                                                     const float* __restrict__ nw,
                                                     unsigned short* __restrict__ normed) {
  const int s = blockIdx.x, tid = threadIdx.x;
  const int lane = tid & 63, wave = tid >> 6;
  const float* g = gates + (size_t)s * MIXN;
  const float p0 = g[0], p1 = g[1], p2 = g[2], p3 = g[3];
  const size_t base = (size_t)s * HC_N * H_DIM;

  f32x4 red[4];
  float ssq = 0.f;
#pragma unroll
  for (int it = 0; it < 4; ++it) {
    const int d4 = it * 256 + tid;
    f32x4 a = *(const f32x4*)(hs + base + (size_t)0 * H_DIM + (size_t)d4 * 4);
    f32x4 b = *(const f32x4*)(hs + base + (size_t)1 * H_DIM + (size_t)d4 * 4);
    f32x4 c = *(const f32x4*)(hs + base + (size_t)2 * H_DIM + (size_t)d4 * 4);
    f32x4 d = *(const f32x4*)(hs + base + (size_t)3 * H_DIM + (size_t)d4 * 4);
    f32x4 v = p0 * a + p1 * b + p2 * c + p3 * d;
    red[it] = v;
    ssq += v.x * v.x + v.y * v.y + v.z * v.z + v.w * v.w;
  }
#pragma unroll
  for (int off = 32; off >= 1; off >>= 1) ssq += __shfl_xor(ssq, off, 64);
  __shared__ float ls[4];
  if (lane == 0) ls[wave] = ssq;
  __syncthreads();
  const float tot = ls[0] + ls[1] + ls[2] + ls[3];
  const float nr = rsqrtf(tot * (1.0f / H_DIM) + 1e-6f);
#pragma unroll
  for (int it = 0; it < 4; ++it) {
    const int d4 = it * 256 + tid;
    f32x4 w = *(const f32x4*)(nw + (size_t)d4 * 4);
    f32x4 v = red[it] * nr;
    v = v * w;
    u16x4 o;
    o[0] = f2bf(v.x); o[1] = f2bf(v.y); o[2] = f2bf(v.z); o[3] = f2bf(v.w);
    *(u16x4*)(normed + (size_t)s * H_DIM + (size_t)d4 * 4) = o;
  }
}

// ---------------------------------------------------------------------------
// K4: bf16 GEMM  C[s][e] = sum_d A[s][d] * B[e][d]
// 256x256 tile, BK=32, 8 waves (2x4), 4-slot LDS ring (128KB), counted
// vmcnt(8) + raw s_barrier once per K-step (never drains to 0 in the loop).
// Ring safety: slot written at step t holds tile t+3; previous occupant
// (tile t-1) was last read at step t-1, separated by that step's barrier.
// Arrival: vmcnt(8) at end of step t retires all but the 2 youngest stage
// groups -> tile t+1 (staged by every wave) visible after the barrier.
__device__ __forceinline__ void gload_lds16(const unsigned short* g, unsigned short* l) {
  __builtin_amdgcn_global_load_lds(
      (const __attribute__((address_space(1))) unsigned int*)(const void*)g,
      (__attribute__((address_space(3))) unsigned int*)(void*)l, 16, 0, 0);
}

#define GEMM_NT 128   // 4096 / 32 K-steps

__global__ __launch_bounds__(512, 2) void k_gemm(const unsigned short* __restrict__ A,
                                                 const unsigned short* __restrict__ B,
                                                 unsigned short* __restrict__ C) {
  __shared__ __align__(16) unsigned short sA[4][256 * 32];
  __shared__ __align__(16) unsigned short sB[4][256 * 32];
  const int tid = threadIdx.x;
  const int lane = tid & 63, wave = tid >> 6;

  // Bijective XCD swizzle (256 blocks % 8 == 0): XCD v owns bn in {2v,2v+1}
  // -> 2 B-column panels (4MB) pinned per XCD L2; A panels stream via L3.
  const int bid = blockIdx.x;
  const int v = bid & 7, u = bid >> 3;          // u in 0..31
  const int bm = u & 15, bn = v * 2 + (u >> 4);
  const int wm = wave >> 2, wn = wave & 3;      // 2x4 wave grid, 128x64 per wave

  // staging geometry: wave stages A rows [wave*32,+32) and B rows likewise,
  // 2 instructions each (1KB = 16 rows x 64B per instruction)
  const int srow = lane >> 2;        // 0..15 within a 16-row chunk
  const int sk = (lane & 3) * 8;     // bf16 k-offset (16B granules)
  const unsigned short* ga = A + (size_t)(bm * 256 + wave * 32 + srow) * 4096 + sk;
  const unsigned short* gb = B + (size_t)(bn * 256 + wave * 32 + srow) * 4096 + sk;
  const int ldst0 = wave * 1024 + lane * 8;   // LDS element offset, instr 0
  const int ldst1 = ldst0 + 512;              // rows +16..31

#define STAGE(slot, t) do {                                        \
    const unsigned short* gha = ga + (size_t)(t) * 32;             \
    const unsigned short* ghb = gb + (size_t)(t) * 32;             \
    gload_lds16(gha,             &sA[(slot)][ldst0]);              \
    gload_lds16(gha + 16 * 4096, &sA[(slot)][ldst1]);              \
    gload_lds16(ghb,             &sB[(slot)][ldst0]);              \
    gload_lds16(ghb + 16 * 4096, &sB[(slot)][ldst1]);              \
  } while (0)

  f32x4 acc[8][4];
  f32x4 zero = {0.f, 0.f, 0.f, 0.f};
#pragma unroll
  for (int mf = 0; mf < 8; mf++)
#pragma unroll
    for (int nf = 0; nf < 4; nf++) acc[mf][nf] = zero;

  const int frow = lane & 15, fk = (lane >> 4) * 8;
  const int abase = wm * 128 + frow;   // + mf*16, row stride 32 elements
  const int bbase = wn * 64 + frow;    // + nf*16

#define COMPUTE(slot) do {                                                    \
    bf16x8 af[8], bfr[4];                                                     \
    _Pragma("unroll") for (int mf = 0; mf < 8; mf++)                          \
      af[mf] = *(const bf16x8*)&sA[(slot)][(abase + mf * 16) * 32 + fk];      \
    _Pragma("unroll") for (int nf = 0; nf < 4; nf++)                          \
      bfr[nf] = *(const bf16x8*)&sB[(slot)][(bbase + nf * 16) * 32 + fk];     \
    __builtin_amdgcn_s_setprio(1);                                            \
    _Pragma("unroll") for (int mf = 0; mf < 8; mf++)                          \
      _Pragma("unroll") for (int nf = 0; nf < 4; nf++)                        \
        acc[mf][nf] = __builtin_amdgcn_mfma_f32_16x16x32_bf16(af[mf], bfr[nf], acc[mf][nf], 0, 0, 0); \
    __builtin_amdgcn_s_setprio(0);                                            \
  } while (0)

  // prologue: stage tiles 0,1,2 (12 instr/wave); wait for tile 0 only
  STAGE(0, 0);
  STAGE(1, 1);
  STAGE(2, 2);
  asm volatile("s_waitcnt vmcnt(8)" ::: "memory");
  asm volatile("s_barrier" ::: "memory");

  for (int t = 0; t < GEMM_NT - 3; ++t) {   // t = 0..124
    STAGE((t + 3) & 3, t + 3);
    COMPUTE(t & 3);
    asm volatile("s_waitcnt vmcnt(8)" ::: "memory");
    asm volatile("s_barrier" ::: "memory");
  }
  COMPUTE((GEMM_NT - 3) & 3);               // t = 125
  asm volatile("s_waitcnt vmcnt(4)" ::: "memory");
  asm volatile("s_barrier" ::: "memory");
  COMPUTE((GEMM_NT - 2) & 3);               // t = 126
  asm volatile("s_waitcnt vmcnt(0)" ::: "memory");
  asm volatile("s_barrier" ::: "memory");
  COMPUTE((GEMM_NT - 1) & 3);               // t = 127

#undef STAGE
#undef COMPUTE

  // epilogue: C write (bf16)
  const int crow0 = bm * 256 + wm * 128 + (lane >> 4) * 4;
  const int ccol0 = bn * 256 + wn * 64 + (lane & 15);
#pragma unroll
  for (int mf = 0; mf < 8; mf++)
#pragma unroll
    for (int nf = 0; nf < 4; nf++)
#pragma unroll
      for (int j = 0; j < 4; j++)
        C[(size_t)(crow0 + mf * 16 + j) * 4096 + ccol0 + nf * 16] = f2bf(acc[mf][nf][j]);
}

// ---------------------------------------------------------------------------
// K5: expanded[s][h][d] = post[h]*out[s][d] + sum_k comb[h][k]*hs[s][k][d]
__global__ __launch_bounds__(256) void k_expand(const float* __restrict__ hs,
                                                const unsigned short* __restrict__ outb,
                                                const float* __restrict__ gates,
                                                float* __restrict__ y) {
  const int s = blockIdx.x, tid = threadIdx.x;
  const float* g = gates + (size_t)s * MIXN;
  float post[4], cb[4][4];
#pragma unroll
  for (int h = 0; h < 4; h++) post[h] = g[4 + h];
#pragma unroll
  for (int h = 0; h < 4; h++)
#pragma unroll
    for (int k = 0; k < 4; k++) cb[h][k] = g[8 + h * 4 + k];

  const size_t base = (size_t)s * HC_N * H_DIM;
#pragma unroll
  for (int it = 0; it < 4; ++it) {
    const int d4 = it * 256 + tid;
    f32x4 hv[4];
#pragma unroll
    for (int k = 0; k < 4; k++)
      hv[k] = *(const f32x4*)(hs + base + (size_t)k * H_DIM + (size_t)d4 * 4);
    u16x4 ob = *(const u16x4*)(outb + (size_t)s * H_DIM + (size_t)d4 * 4);
    f32x4 o = {bf2f(ob[0]), bf2f(ob[1]), bf2f(ob[2]), bf2f(ob[3])};
#pragma unroll
    for (int h = 0; h < 4; h++) {
      f32x4 e = post[h] * o + cb[h][0] * hv[0] + cb[h][1] * hv[1] + cb[h][2] * hv[2] + cb[h][3] * hv[3];
      *(f32x4*)(y + base + (size_t)h * H_DIM + (size_t)d4 * 4) = e;
    }
  }
}

// ---------------------------------------------------------------------------
extern "C" void kernel_launch(void* const* d_in, const int* in_sizes, int n_in,
                              void* d_out, int out_size, void* d_ws, size_t ws_size,
                              hipStream_t stream) {
  const float* hs = (const float*)d_in[0];      // [1,4096,4,4096]
  const float* fn = (const float*)d_in[1];      // [24,16384]
  const float* hbase = (const float*)d_in[2];   // [24]
  const float* hscale = (const float*)d_in[3];  // [3]
  const float* nw = (const float*)d_in[4];      // [4096]
  const float* wi = (const float*)d_in[5];      // [4096,4096]
  float* y = (float*)d_out;                     // [1,4096,4,4096] fp32

  char* ws = (char*)d_ws;
  float* mixraw = (float*)(ws);                            // 4096*24*4   = 393216
  float* sumsq = (float*)(ws + 393216);                    // 4096*4      = 16384
  float* gates = (float*)(ws + 409600);                    // 4096*24*4   = 393216
  unsigned short* normed = (unsigned short*)(ws + 1048576);            // 32MB bf16
  unsigned short* wb = (unsigned short*)(ws + 1048576 + 33554432);     // 32MB bf16
  unsigned short* outb = (unsigned short*)(ws + 1048576 + 2 * 33554432); // 32MB bf16
  // total ws use: ~97MB

  k_w2bf<<<8192, 256, 0, stream>>>(wi, wb);
  k_mixes<<<1024, 256, 0, stream>>>(hs, fn, mixraw, sumsq);
  k_gates<<<16, 256, 0, stream>>>(mixraw, sumsq, hbase, hscale, gates);
  k_reduce_norm<<<4096, 256, 0, stream>>>(hs, gates, nw, normed);
  k_gemm<<<256, 512, 0, stream>>>(normed, wb, outb);
  k_expand<<<4096, 256, 0, stream>>>(hs, outb, gates, y);
}